// Round 1
// baseline (188.769 us; speedup 1.0000x reference)
//
#include <hip/hip_runtime.h>
#include <stdint.h>

#define SEQ 2048
#define DMODEL 1024
#define NHEAD 16
#define HDIM 64

typedef unsigned short u16;
typedef __attribute__((ext_vector_type(4))) float f32x4;
typedef __attribute__((ext_vector_type(8))) __bf16 bf16x8;
typedef __attribute__((ext_vector_type(8))) u16 u16x8;

__device__ __forceinline__ u16 f2bf(float f) {
  unsigned int u = __builtin_bit_cast(unsigned int, f);
  unsigned int r = (u + 0x7FFFu + ((u >> 16) & 1u)) >> 16;
  return (u16)r;
}
__device__ __forceinline__ float bf2f(u16 b) {
  unsigned int u = ((unsigned int)b) << 16;
  return __builtin_bit_cast(float, u);
}
__device__ __forceinline__ bf16x8 load8(const u16* p) {
  return __builtin_bit_cast(bf16x8, *(const u16x8*)p);
}
__device__ __forceinline__ void gl_lds16(const void* g, void* l) {
  __builtin_amdgcn_global_load_lds(
      (const __attribute__((address_space(1))) unsigned int*)g,
      (__attribute__((address_space(3))) unsigned int*)l, 16, 0, 0);
}

// ---------------- f32 -> bf16 convert (hidden_states) ----------------
__global__ __launch_bounds__(256) void convert_x(const float* __restrict__ X,
                                                 u16* __restrict__ Xb) {
  int i = (blockIdx.x * 256 + threadIdx.x) * 4;
  float4 v = *(const float4*)(X + i);
  union { u16 s[4]; uint2 u; } o;
  o.s[0] = f2bf(v.x); o.s[1] = f2bf(v.y); o.s[2] = f2bf(v.z); o.s[3] = f2bf(v.w);
  *(uint2*)(Xb + i) = o.u;
}

// ------------- weight transpose+convert: W[k][n] f32 -> Wt[n][k] bf16 -------------
__global__ __launch_bounds__(256) void transpose_w(
    const float* __restrict__ W0, const float* __restrict__ W1,
    const float* __restrict__ W2, const float* __restrict__ W3,
    u16* __restrict__ T0, u16* __restrict__ T1,
    u16* __restrict__ T2, u16* __restrict__ T3) {
  __shared__ u16 tile[64][65];
  int bz = blockIdx.z;
  const float* W = bz == 0 ? W0 : bz == 1 ? W1 : bz == 2 ? W2 : W3;
  u16* T = bz == 0 ? T0 : bz == 1 ? T1 : bz == 2 ? T2 : T3;
  int n0 = blockIdx.x * 64, k0 = blockIdx.y * 64;
  int t = threadIdx.x;
#pragma unroll 4
  for (int i = 0; i < 16; ++i) {
    int idx = i * 256 + t;
    int r = idx >> 6, c = idx & 63;
    tile[r][c] = f2bf(W[(k0 + r) * 1024 + n0 + c]);
  }
  __syncthreads();
#pragma unroll 4
  for (int i = 0; i < 16; ++i) {
    int idx = i * 256 + t;
    int r = idx >> 6, c = idx & 63;  // r = n-local, c = k-local
    T[(n0 + r) * 1024 + k0 + c] = tile[c][r];
  }
}

// ---------------- bf16 MFMA GEMM: C[M][n] = A[M][K] * W[K][n], B given as Wt[n][k] ----------------
// 128x128 tile, BK=32, 4 waves (2x2), each wave 64x64. NMATS=3 -> QKV fused (N=3072).
template <int NMATS, bool OUTF32>
__global__ __launch_bounds__(256) void gemm_bf16(
    const u16* __restrict__ A, const u16* __restrict__ B0,
    const u16* __restrict__ B1, const u16* __restrict__ B2,
    u16* __restrict__ O0, u16* __restrict__ O1, u16* __restrict__ O2,
    float* __restrict__ OF) {
  __shared__ u16 As[128 * 32];
  __shared__ u16 Bs[128 * 32];
  const int t = threadIdx.x;
  const int lane = t & 63, w = t >> 6;
  const int g = lane >> 4, li = lane & 15;
  const int n0g = blockIdx.x * 128;
  const int mat = n0g >> 10;
  const int n0 = n0g & 1023;
  const u16* Bp = (NMATS == 1 || mat == 0) ? B0 : (mat == 1 ? B1 : B2);
  const int m0 = blockIdx.y * 128;
  const int wm = (w >> 1) * 64, wn = (w & 1) * 64;
  f32x4 acc[4][4] = {};
  for (int k0 = 0; k0 < 1024; k0 += 32) {
#pragma unroll
    for (int it = 0; it < 2; ++it) {
      int L = it * 2048 + t * 8;   // bf16 element index within 128x32 tile
      int r = L >> 5, c = L & 31;
      gl_lds16(A + (m0 + r) * 1024 + k0 + c, (char*)As + it * 4096 + w * 1024);
      gl_lds16(Bp + (n0 + r) * 1024 + k0 + c, (char*)Bs + it * 4096 + w * 1024);
    }
    __syncthreads();
    bf16x8 af[4], bfr[4];
#pragma unroll
    for (int mi = 0; mi < 4; ++mi) af[mi] = load8(&As[(wm + mi * 16 + li) * 32 + g * 8]);
#pragma unroll
    for (int ni = 0; ni < 4; ++ni) bfr[ni] = load8(&Bs[(wn + ni * 16 + li) * 32 + g * 8]);
#pragma unroll
    for (int mi = 0; mi < 4; ++mi)
#pragma unroll
      for (int ni = 0; ni < 4; ++ni)
        acc[mi][ni] = __builtin_amdgcn_mfma_f32_16x16x32_bf16(af[mi], bfr[ni], acc[mi][ni], 0, 0, 0);
    __syncthreads();
  }
  u16* Ob = (NMATS == 1 || mat == 0) ? O0 : (mat == 1 ? O1 : O2);
#pragma unroll
  for (int mi = 0; mi < 4; ++mi)
#pragma unroll
    for (int ni = 0; ni < 4; ++ni)
#pragma unroll
      for (int r = 0; r < 4; ++r) {
        // verified C/D layout: row = (lane>>4)*4 + r, col = lane&15
        int m = m0 + wm + mi * 16 + g * 4 + r;
        int n = n0 + wn + ni * 16 + li;
        float v = acc[mi][ni][r];
        if (OUTF32) OF[m * 1024 + n] = v;
        else Ob[m * 1024 + n] = f2bf(v);
      }
}

// ---------------- RoPE in-place on bf16 Q,K; fold 1/sqrt(HD) into Q ----------------
__global__ __launch_bounds__(256) void rope_qk(u16* __restrict__ Qb, u16* __restrict__ Kb,
                                               const int* __restrict__ pos_ids) {
  int gid = blockIdx.x * 256 + threadIdx.x;  // 2048*512 threads, one per (s,h,pair)
  int s = gid >> 9;
  int rem = gid & 511;
  int h = rem >> 5, i = rem & 31;
  float pos = (float)pos_ids[s];
  // inv_freq = 10000^(-i/32) = exp2(-i/32 * log2(10000))
  float inv = exp2f(-(float)i * (13.287712379549449f / 32.0f));
  float ang = pos * inv;
  float sn, cs;
  sincosf(ang, &sn, &cs);
  int base = s * 1024 + h * 64 + 2 * i;
  {
    float x0 = bf2f(Qb[base]), x1 = bf2f(Qb[base + 1]);
    Qb[base]     = f2bf((x0 * cs - x1 * sn) * 0.125f);
    Qb[base + 1] = f2bf((x0 * sn + x1 * cs) * 0.125f);
  }
  {
    float x0 = bf2f(Kb[base]), x1 = bf2f(Kb[base + 1]);
    Kb[base]     = f2bf(x0 * cs - x1 * sn);
    Kb[base + 1] = f2bf(x0 * sn + x1 * cs);
  }
}

// ---------------- V transpose: Vb[s][h*64+d] -> Vt[h][d][s] ----------------
__global__ __launch_bounds__(256) void v_transpose(const u16* __restrict__ Vb,
                                                   u16* __restrict__ Vt) {
  __shared__ u16 tile[64][65];
  const int t = threadIdx.x;
  const int s0 = blockIdx.x * 64, h = blockIdx.y;
#pragma unroll 4
  for (int i = 0; i < 16; ++i) {
    int idx = i * 256 + t;
    int r = idx >> 6, c = idx & 63;
    tile[r][c] = Vb[(s0 + r) * 1024 + h * 64 + c];
  }
  __syncthreads();
#pragma unroll 4
  for (int i = 0; i < 16; ++i) {
    int idx = i * 256 + t;
    int d = idx >> 6, sc = idx & 63;
    Vt[h * (64 * 2048) + d * 2048 + s0 + sc] = tile[sc][d];
  }
}

// ---------------- flash attention: 1 wave per (head, 16-query block) ----------------
__global__ __launch_bounds__(256) void attn_fwd(
    const u16* __restrict__ Qb, const u16* __restrict__ Kb,
    const u16* __restrict__ Vt, const int* __restrict__ amask,
    u16* __restrict__ Ab) {
  __shared__ u16 Plds[4][16][40];  // per-wave P tile [q=16][kk=32], stride 40 kills conflicts
  const int t = threadIdx.x, lane = t & 63, w = t >> 6;
  const int g = lane >> 4, li = lane & 15;
  const int h = blockIdx.y;
  const int qg = gridDim.x - 1 - blockIdx.x;  // heavy q-blocks dispatch first
  const int qb = (qg * 4 + w) * 16;
  // Q A-fragments (scale already folded): lane reads Q[qb+li][h*64 + d0 + g*8 .. +7]
  bf16x8 qf0 = load8(Qb + (qb + li) * 1024 + h * 64 + 0 + g * 8);
  bf16x8 qf1 = load8(Qb + (qb + li) * 1024 + h * 64 + 32 + g * 8);
  f32x4 acc[4] = {};
  float mrow[4] = {-1e30f, -1e30f, -1e30f, -1e30f};
  float lrow[4] = {0.f, 0.f, 0.f, 0.f};
  const int nkv = qb + 16;
  for (int k0 = 0; k0 < nkv; k0 += 32) {
    f32x4 sc[2] = {};
#pragma unroll
    for (int sub = 0; sub < 2; ++sub) {
      bf16x8 kf0 = load8(Kb + (k0 + sub * 16 + li) * 1024 + h * 64 + 0 + g * 8);
      bf16x8 kf1 = load8(Kb + (k0 + sub * 16 + li) * 1024 + h * 64 + 32 + g * 8);
      sc[sub] = __builtin_amdgcn_mfma_f32_16x16x32_bf16(qf0, kf0, sc[sub], 0, 0, 0);
      sc[sub] = __builtin_amdgcn_mfma_f32_16x16x32_bf16(qf1, kf1, sc[sub], 0, 0, 0);
    }
    // mask + online softmax. Score layout: row(q) = g*4+r, col(key) = li.
    float sv[2][4];
    float tmax[4] = {-1e30f, -1e30f, -1e30f, -1e30f};
#pragma unroll
    for (int sub = 0; sub < 2; ++sub) {
      int key = k0 + sub * 16 + li;
      bool kok = (amask[key] != 0);
#pragma unroll
      for (int r = 0; r < 4; ++r) {
        int q = qb + g * 4 + r;
        float v = (kok && key <= q) ? sc[sub][r] : -1e30f;
        sv[sub][r] = v;
        tmax[r] = fmaxf(tmax[r], v);
      }
    }
#pragma unroll
    for (int m = 1; m < 16; m <<= 1)
#pragma unroll
      for (int r = 0; r < 4; ++r) tmax[r] = fmaxf(tmax[r], __shfl_xor(tmax[r], m, 64));
    float alpha[4];
#pragma unroll
    for (int r = 0; r < 4; ++r) {
      float mn = fmaxf(mrow[r], tmax[r]);
      alpha[r] = __expf(mrow[r] - mn);  // first tile: exp(-huge) = 0
      mrow[r] = mn;
    }
    float ps[4] = {0.f, 0.f, 0.f, 0.f};
#pragma unroll
    for (int sub = 0; sub < 2; ++sub)
#pragma unroll
      for (int r = 0; r < 4; ++r) {
        float p = __expf(sv[sub][r] - mrow[r]);  // masked -> exp(-huge) = 0
        ps[r] += p;
        Plds[w][g * 4 + r][sub * 16 + li] = f2bf(p);
      }
#pragma unroll
    for (int m = 1; m < 16; m <<= 1)
#pragma unroll
      for (int r = 0; r < 4; ++r) ps[r] += __shfl_xor(ps[r], m, 64);
#pragma unroll
    for (int r = 0; r < 4; ++r) lrow[r] = lrow[r] * alpha[r] + ps[r];
#pragma unroll
    for (int ti = 0; ti < 4; ++ti)
#pragma unroll
      for (int r = 0; r < 4; ++r) acc[ti][r] *= alpha[r];
    // P A-fragment from LDS (same-wave RAW; compiler inserts lgkmcnt waits)
    bf16x8 pf = load8(&Plds[w][li][g * 8]);
#pragma unroll
    for (int ti = 0; ti < 4; ++ti) {
      bf16x8 vf = load8(Vt + h * (64 * 2048) + (ti * 16 + li) * 2048 + k0 + g * 8);
      acc[ti] = __builtin_amdgcn_mfma_f32_16x16x32_bf16(pf, vf, acc[ti], 0, 0, 0);
    }
  }
#pragma unroll
  for (int ti = 0; ti < 4; ++ti)
#pragma unroll
    for (int r = 0; r < 4; ++r) {
      int q = qb + g * 4 + r;
      Ab[q * 1024 + h * 64 + ti * 16 + li] = f2bf(acc[ti][r] / lrow[r]);
    }
}

extern "C" void kernel_launch(void* const* d_in, const int* in_sizes, int n_in,
                              void* d_out, int out_size, void* d_ws, size_t ws_size,
                              hipStream_t stream) {
  const float* X = (const float*)d_in[0];
  const int* amask = (const int*)d_in[1];
  const int* pos = (const int*)d_in[2];
  const float* wq = (const float*)d_in[3];
  const float* wk = (const float*)d_in[4];
  const float* wv = (const float*)d_in[5];
  const float* wo = (const float*)d_in[6];
  float* out = (float*)d_out;
  char* ws = (char*)d_ws;
  // workspace layout (32 MB total)
  u16* Xb  = (u16*)(ws);                  // 4 MB  X bf16 [2048][1024]
  u16* Wtq = (u16*)(ws + (4u  << 20));    // 2 MB  Wt [n][k]
  u16* Wtk = (u16*)(ws + (6u  << 20));
  u16* Wtv = (u16*)(ws + (8u  << 20));
  u16* Wto = (u16*)(ws + (10u << 20));
  u16* Qb  = (u16*)(ws + (12u << 20));    // 4 MB  [2048][1024] (RoPE'd, x1/8)
  u16* Kb  = (u16*)(ws + (16u << 20));    // 4 MB
  u16* Vb  = (u16*)(ws + (20u << 20));    // 4 MB
  u16* Vt  = (u16*)(ws + (24u << 20));    // 4 MB  [16][64][2048]
  u16* Ab  = (u16*)(ws + (28u << 20));    // 4 MB  attn out bf16

  convert_x<<<2048, 256, 0, stream>>>(X, Xb);
  transpose_w<<<dim3(16, 16, 4), 256, 0, stream>>>(wq, wk, wv, wo, Wtq, Wtk, Wtv, Wto);
  gemm_bf16<3, false><<<dim3(24, 16), 256, 0, stream>>>(Xb, Wtq, Wtk, Wtv, Qb, Kb, Vb, nullptr);
  rope_qk<<<4096, 256, 0, stream>>>(Qb, Kb, pos);
  v_transpose<<<dim3(32, 16), 256, 0, stream>>>(Vb, Vt);
  attn_fwd<<<dim3(32, 16), 256, 0, stream>>>(Qb, Kb, Vt, amask, Ab);
  gemm_bf16<1, true><<<dim3(8, 16), 256, 0, stream>>>(Ab, Wto, nullptr, nullptr,
                                                      nullptr, nullptr, nullptr, out);
}

// Round 7
// 159.761 us; speedup vs baseline: 1.1816x; 1.1816x over previous
//
#include <hip/hip_runtime.h>
#include <stdint.h>

#define SEQ 2048
#define DMODEL 1024
#define NHEAD 16
#define HDIM 64
#define CH 512   // key-chunk per attn_partial wave
#define NCH 4    // max chunks (SEQ/CH)

typedef unsigned short u16;
typedef __attribute__((ext_vector_type(4))) float f32x4;
typedef __attribute__((ext_vector_type(8))) __bf16 bf16x8;
typedef __attribute__((ext_vector_type(8))) u16 u16x8;

__device__ __forceinline__ u16 f2bf(float f) {
  unsigned int u = __builtin_bit_cast(unsigned int, f);
  unsigned int r = (u + 0x7FFFu + ((u >> 16) & 1u)) >> 16;
  return (u16)r;
}
__device__ __forceinline__ float bf2f(u16 b) {
  unsigned int u = ((unsigned int)b) << 16;
  return __builtin_bit_cast(float, u);
}
__device__ __forceinline__ bf16x8 load8(const u16* p) {
  return __builtin_bit_cast(bf16x8, *(const u16x8*)p);
}
__device__ __forceinline__ void gl_lds16(const void* g, void* l) {
  __builtin_amdgcn_global_load_lds(
      (const __attribute__((address_space(1))) unsigned int*)g,
      (__attribute__((address_space(3))) unsigned int*)l, 16, 0, 0);
}

// ---------------- f32 -> bf16 convert (hidden_states) ----------------
__global__ __launch_bounds__(256) void convert_x(const float* __restrict__ X,
                                                 u16* __restrict__ Xb) {
  int i = (blockIdx.x * 256 + threadIdx.x) * 4;
  float4 v = *(const float4*)(X + i);
  union { u16 s[4]; uint2 u; } o;
  o.s[0] = f2bf(v.x); o.s[1] = f2bf(v.y); o.s[2] = f2bf(v.z); o.s[3] = f2bf(v.w);
  *(uint2*)(Xb + i) = o.u;
}

// ------------- weight transpose+convert: W[k][n] f32 -> Wt[n][k] bf16 -------------
__global__ __launch_bounds__(256) void transpose_w(
    const float* __restrict__ W0, const float* __restrict__ W1,
    const float* __restrict__ W2, const float* __restrict__ W3,
    u16* __restrict__ T0, u16* __restrict__ T1,
    u16* __restrict__ T2, u16* __restrict__ T3) {
  __shared__ u16 tile[64][65];
  int bz = blockIdx.z;
  const float* W = bz == 0 ? W0 : bz == 1 ? W1 : bz == 2 ? W2 : W3;
  u16* T = bz == 0 ? T0 : bz == 1 ? T1 : bz == 2 ? T2 : T3;
  int n0 = blockIdx.x * 64, k0 = blockIdx.y * 64;
  int t = threadIdx.x;
#pragma unroll 4
  for (int i = 0; i < 16; ++i) {
    int idx = i * 256 + t;
    int r = idx >> 6, c = idx & 63;
    tile[r][c] = f2bf(W[(k0 + r) * 1024 + n0 + c]);
  }
  __syncthreads();
#pragma unroll 4
  for (int i = 0; i < 16; ++i) {
    int idx = i * 256 + t;
    int r = idx >> 6, c = idx & 63;  // r = n-local, c = k-local
    T[(n0 + r) * 1024 + k0 + c] = tile[c][r];
  }
}

// ---------------- bf16 MFMA GEMM: C[M][n] = A[M][K] * W[K][n], B given as Wt[n][k] ----------------
// BMxBN tile, BK=32, 4 waves (2x2), each wave (BM/2)x(BN/2). NMATS=3 -> QKV fused.
template <int BM, int BN, int NMATS, bool OUTF32>
__global__ __launch_bounds__(256) void gemm_bf16(
    const u16* __restrict__ A, const u16* __restrict__ B0,
    const u16* __restrict__ B1, const u16* __restrict__ B2,
    u16* __restrict__ O0, u16* __restrict__ O1, u16* __restrict__ O2,
    float* __restrict__ OF) {
  constexpr int MI = BM / 32, NI = BN / 32;
  constexpr int LA = BM / 64, LB = BN / 64;
  __shared__ u16 As[BM * 32];
  __shared__ u16 Bs[BN * 32];
  const int t = threadIdx.x;
  const int lane = t & 63, w = t >> 6;
  const int g = lane >> 4, li = lane & 15;
  const int n0g = blockIdx.x * BN;
  const int mat = n0g >> 10;
  const int n0 = n0g & 1023;
  const u16* Bp = (NMATS == 1 || mat == 0) ? B0 : (mat == 1 ? B1 : B2);
  const int m0 = blockIdx.y * BM;
  const int wm = (w >> 1) * (BM / 2), wn = (w & 1) * (BN / 2);
  f32x4 acc[MI][NI] = {};
  for (int k0 = 0; k0 < 1024; k0 += 32) {
#pragma unroll
    for (int it = 0; it < LA; ++it) {
      int L = it * 2048 + t * 8;   // bf16 element index within BMx32 tile
      int r = L >> 5, c = L & 31;
      gl_lds16(A + (m0 + r) * 1024 + k0 + c, (char*)As + it * 4096 + w * 1024);
    }
#pragma unroll
    for (int it = 0; it < LB; ++it) {
      int L = it * 2048 + t * 8;
      int r = L >> 5, c = L & 31;
      gl_lds16(Bp + (n0 + r) * 1024 + k0 + c, (char*)Bs + it * 4096 + w * 1024);
    }
    __syncthreads();
    bf16x8 af[MI], bfr[NI];
#pragma unroll
    for (int mi = 0; mi < MI; ++mi) af[mi] = load8(&As[(wm + mi * 16 + li) * 32 + g * 8]);
#pragma unroll
    for (int ni = 0; ni < NI; ++ni) bfr[ni] = load8(&Bs[(wn + ni * 16 + li) * 32 + g * 8]);
#pragma unroll
    for (int mi = 0; mi < MI; ++mi)
#pragma unroll
      for (int ni = 0; ni < NI; ++ni)
        acc[mi][ni] = __builtin_amdgcn_mfma_f32_16x16x32_bf16(af[mi], bfr[ni], acc[mi][ni], 0, 0, 0);
    __syncthreads();
  }
  u16* Ob = (NMATS == 1 || mat == 0) ? O0 : (mat == 1 ? O1 : O2);
#pragma unroll
  for (int mi = 0; mi < MI; ++mi)
#pragma unroll
    for (int ni = 0; ni < NI; ++ni)
#pragma unroll
      for (int r = 0; r < 4; ++r) {
        // verified C/D layout: row = (lane>>4)*4 + r, col = lane&15
        int m = m0 + wm + mi * 16 + g * 4 + r;
        int n = n0 + wn + ni * 16 + li;
        float v = acc[mi][ni][r];
        if (OUTF32) OF[m * 1024 + n] = v;
        else Ob[m * 1024 + n] = f2bf(v);
      }
}

// ---------------- RoPE in-place on bf16 Q,K; fold 1/sqrt(HD) into Q ----------------
__global__ __launch_bounds__(256) void rope_qk(u16* __restrict__ Qb, u16* __restrict__ Kb,
                                               const int* __restrict__ pos_ids) {
  int gid = blockIdx.x * 256 + threadIdx.x;  // one per (s,h,pair)
  int s = gid >> 9;
  int rem = gid & 511;
  int h = rem >> 5, i = rem & 31;
  float pos = (float)pos_ids[s];
  float inv = exp2f(-(float)i * (13.287712379549449f / 32.0f));
  float ang = pos * inv;
  float sn, cs;
  sincosf(ang, &sn, &cs);
  int base = s * 1024 + h * 64 + 2 * i;
  {
    float x0 = bf2f(Qb[base]), x1 = bf2f(Qb[base + 1]);
    Qb[base]     = f2bf((x0 * cs - x1 * sn) * 0.125f);
    Qb[base + 1] = f2bf((x0 * sn + x1 * cs) * 0.125f);
  }
  {
    float x0 = bf2f(Kb[base]), x1 = bf2f(Kb[base + 1]);
    Kb[base]     = f2bf(x0 * cs - x1 * sn);
    Kb[base + 1] = f2bf(x0 * sn + x1 * cs);
  }
}

// ---------------- V transpose: Vb[s][h*64+d] -> Vt[h][d][s] ----------------
__global__ __launch_bounds__(256) void v_transpose(const u16* __restrict__ Vb,
                                                   u16* __restrict__ Vt) {
  __shared__ u16 tile[64][65];
  const int t = threadIdx.x;
  const int s0 = blockIdx.x * 64, h = blockIdx.y;
#pragma unroll 4
  for (int i = 0; i < 16; ++i) {
    int idx = i * 256 + t;
    int r = idx >> 6, c = idx & 63;
    tile[r][c] = Vb[(s0 + r) * 1024 + h * 64 + c];
  }
  __syncthreads();
#pragma unroll 4
  for (int i = 0; i < 16; ++i) {
    int idx = i * 256 + t;
    int d = idx >> 6, sc = idx & 63;
    Vt[h * (64 * 2048) + d * 2048 + s0 + sc] = tile[sc][d];
  }
}

// ---------------- split-K flash attention partial: 1 wave per (head, qb16, key-chunk) ----------------
__global__ __launch_bounds__(64) void attn_partial(
    const u16* __restrict__ Qb, const u16* __restrict__ Kb,
    const u16* __restrict__ Vt, const int* __restrict__ amask,
    float* __restrict__ Mpart, float* __restrict__ Lpart, u16* __restrict__ Opart) {
  const int lane = threadIdx.x & 63;
  const int g = lane >> 4, li = lane & 15;
  const int qb = blockIdx.x, chunk = blockIdx.y, h = blockIdx.z;
  const int qlim = qb * 16 + 16;
  const int kstart = chunk * CH;
  if (kstart >= qlim) return;
  const int kend = min(kstart + CH, qlim);
  __shared__ u16 Plds[16][40];  // P tile [q=16][kk=32], stride 40 kills conflicts
  const int qb16 = qb * 16;
  bf16x8 qf0 = load8(Qb + (qb16 + li) * 1024 + h * 64 + 0 + g * 8);
  bf16x8 qf1 = load8(Qb + (qb16 + li) * 1024 + h * 64 + 32 + g * 8);
  f32x4 acc[4] = {};
  float mrow[4] = {-1e30f, -1e30f, -1e30f, -1e30f};
  float lrow[4] = {0.f, 0.f, 0.f, 0.f};
  for (int k0 = kstart; k0 < kend; k0 += 32) {
    f32x4 sc[2] = {};
#pragma unroll
    for (int sub = 0; sub < 2; ++sub) {
      bf16x8 kf0 = load8(Kb + (k0 + sub * 16 + li) * 1024 + h * 64 + 0 + g * 8);
      bf16x8 kf1 = load8(Kb + (k0 + sub * 16 + li) * 1024 + h * 64 + 32 + g * 8);
      sc[sub] = __builtin_amdgcn_mfma_f32_16x16x32_bf16(qf0, kf0, sc[sub], 0, 0, 0);
      sc[sub] = __builtin_amdgcn_mfma_f32_16x16x32_bf16(qf1, kf1, sc[sub], 0, 0, 0);
    }
    // mask + online softmax. Score layout: row(q) = g*4+r, col(key) = li.
    float sv[2][4];
    float tmax[4] = {-1e30f, -1e30f, -1e30f, -1e30f};
#pragma unroll
    for (int sub = 0; sub < 2; ++sub) {
      int key = k0 + sub * 16 + li;
      bool kok = (amask[key] != 0);
#pragma unroll
      for (int r = 0; r < 4; ++r) {
        int q = qb16 + g * 4 + r;
        float v = (kok && key <= q) ? sc[sub][r] : -1e30f;
        sv[sub][r] = v;
        tmax[r] = fmaxf(tmax[r], v);
      }
    }
#pragma unroll
    for (int m = 1; m < 16; m <<= 1)
#pragma unroll
      for (int r = 0; r < 4; ++r) tmax[r] = fmaxf(tmax[r], __shfl_xor(tmax[r], m, 64));
    float alpha[4];
#pragma unroll
    for (int r = 0; r < 4; ++r) {
      float mn = fmaxf(mrow[r], tmax[r]);
      alpha[r] = __expf(mrow[r] - mn);
      mrow[r] = mn;
    }
    float ps[4] = {0.f, 0.f, 0.f, 0.f};
#pragma unroll
    for (int sub = 0; sub < 2; ++sub)
#pragma unroll
      for (int r = 0; r < 4; ++r) {
        float p = __expf(sv[sub][r] - mrow[r]);  // masked -> 0
        ps[r] += p;
        Plds[g * 4 + r][sub * 16 + li] = f2bf(p);
      }
#pragma unroll
    for (int m = 1; m < 16; m <<= 1)
#pragma unroll
      for (int r = 0; r < 4; ++r) ps[r] += __shfl_xor(ps[r], m, 64);
#pragma unroll
    for (int r = 0; r < 4; ++r) lrow[r] = lrow[r] * alpha[r] + ps[r];
#pragma unroll
    for (int ti = 0; ti < 4; ++ti)
#pragma unroll
      for (int r = 0; r < 4; ++r) acc[ti][r] *= alpha[r];
    bf16x8 pf = load8(&Plds[li][g * 8]);  // same-wave RAW; compiler inserts waits
#pragma unroll
    for (int ti = 0; ti < 4; ++ti) {
      bf16x8 vf = load8(Vt + h * (64 * 2048) + (ti * 16 + li) * 2048 + k0 + g * 8);
      acc[ti] = __builtin_amdgcn_mfma_f32_16x16x32_bf16(pf, vf, acc[ti], 0, 0, 0);
    }
  }
  const int idx = (h * 128 + qb) * NCH + chunk;
  if (li == 0) {
#pragma unroll
    for (int r = 0; r < 4; ++r) {
      Mpart[idx * 16 + g * 4 + r] = mrow[r];
      Lpart[idx * 16 + g * 4 + r] = lrow[r];
    }
  }
#pragma unroll
  for (int ti = 0; ti < 4; ++ti)
#pragma unroll
    for (int r = 0; r < 4; ++r)
      Opart[idx * 1024 + (g * 4 + r) * 64 + ti * 16 + li] = f2bf(acc[ti][r]);
}

// ---------------- combine partials -> Ab bf16 [s][h*64+d] ----------------
__global__ __launch_bounds__(256) void attn_combine(
    const float* __restrict__ Mpart, const float* __restrict__ Lpart,
    const u16* __restrict__ Opart, u16* __restrict__ Ab) {
  const int qb = blockIdx.x, h = blockIdx.y;
  const int t = threadIdx.x;
  const int q = t >> 4, dg = t & 15;  // q 0..15, d = dg*4..dg*4+3
  const int nch = (qb * 16 + 16 + CH - 1) / CH;
  const int base = (h * 128 + qb) * NCH;
  float M = -1e30f;
#pragma unroll
  for (int c = 0; c < NCH; ++c)
    if (c < nch) M = fmaxf(M, Mpart[(base + c) * 16 + q]);
  float L = 0.f;
  float o[4] = {0.f, 0.f, 0.f, 0.f};
#pragma unroll
  for (int c = 0; c < NCH; ++c)
    if (c < nch) {
      float e = __expf(Mpart[(base + c) * 16 + q] - M);
      L += e * Lpart[(base + c) * 16 + q];
      const u16* op = Opart + (base + c) * 1024 + q * 64 + dg * 4;
      uint2 pk = *(const uint2*)op;
      const u16* ps = (const u16*)&pk;
#pragma unroll
      for (int j = 0; j < 4; ++j) o[j] += e * bf2f(ps[j]);
    }
  float inv = 1.f / L;
  u16* dst = Ab + (qb * 16 + q) * 1024 + h * 64 + dg * 4;
  union { u16 s[4]; uint2 u; } ou;
#pragma unroll
  for (int j = 0; j < 4; ++j) ou.s[j] = f2bf(o[j] * inv);
  *(uint2*)dst = ou.u;
}

extern "C" void kernel_launch(void* const* d_in, const int* in_sizes, int n_in,
                              void* d_out, int out_size, void* d_ws, size_t ws_size,
                              hipStream_t stream) {
  const float* X = (const float*)d_in[0];
  const int* amask = (const int*)d_in[1];
  const int* pos = (const int*)d_in[2];
  const float* wq = (const float*)d_in[3];
  const float* wk = (const float*)d_in[4];
  const float* wv = (const float*)d_in[5];
  const float* wo = (const float*)d_in[6];
  float* out = (float*)d_out;
  char* ws = (char*)d_ws;
  // workspace layout (~49 MB total)
  u16* Xb  = (u16*)(ws);                  // 4 MB  X bf16 [2048][1024]
  u16* Wtq = (u16*)(ws + (4u  << 20));    // 2 MB  Wt [n][k]
  u16* Wtk = (u16*)(ws + (6u  << 20));
  u16* Wtv = (u16*)(ws + (8u  << 20));
  u16* Wto = (u16*)(ws + (10u << 20));
  u16* Qb  = (u16*)(ws + (12u << 20));    // 4 MB  [2048][1024] (RoPE'd, x1/8)
  u16* Kb  = (u16*)(ws + (16u << 20));    // 4 MB
  u16* Vb  = (u16*)(ws + (20u << 20));    // 4 MB
  u16* Vt  = (u16*)(ws + (24u << 20));    // 4 MB  [16][64][2048]
  u16* Ab  = (u16*)(ws + (28u << 20));    // 4 MB  attn out bf16
  float* Mpart = (float*)(ws + (32u << 20));            // 512 KB [16*128*4][16]
  float* Lpart = (float*)(ws + (32u << 20) + (512u << 10));  // 512 KB
  u16*   Opart = (u16*)(ws + (33u << 20));              // 16 MB [16*128*4][1024]

  convert_x<<<2048, 256, 0, stream>>>(X, Xb);
  transpose_w<<<dim3(16, 16, 4), 256, 0, stream>>>(wq, wk, wv, wo, Wtq, Wtk, Wtv, Wto);
  gemm_bf16<64, 128, 3, false><<<dim3(24, 32), 256, 0, stream>>>(Xb, Wtq, Wtk, Wtv, Qb, Kb, Vb, nullptr);
  rope_qk<<<4096, 256, 0, stream>>>(Qb, Kb, pos);
  v_transpose<<<dim3(32, 16), 256, 0, stream>>>(Vb, Vt);
  attn_partial<<<dim3(128, NCH, 16), 64, 0, stream>>>(Qb, Kb, Vt, amask, Mpart, Lpart, Opart);
  attn_combine<<<dim3(128, 16), 256, 0, stream>>>(Mpart, Lpart, Opart, Ab);
  gemm_bf16<64, 64, 1, true><<<dim3(16, 32), 256, 0, stream>>>(Ab, Wto, nullptr, nullptr,
                                                               nullptr, nullptr, nullptr, out);
}

// Round 8
// 145.583 us; speedup vs baseline: 1.2966x; 1.0974x over previous
//
#include <hip/hip_runtime.h>
#include <stdint.h>

#define SEQ 2048
#define DMODEL 1024
#define NHEAD 16
#define HDIM 64
#define KCH 256    // keys per attn work item
#define NCH 8      // max chunks per q-block (SEQ/KCH)
#define NITEMS 576 // work items per head: sum_{c=0..7}(128-16c)
#define WPH 512    // waves per head: (2048 blocks / 16 heads) * 4 waves

typedef unsigned short u16;
typedef __attribute__((ext_vector_type(4))) float f32x4;
typedef __attribute__((ext_vector_type(8))) __bf16 bf16x8;
typedef __attribute__((ext_vector_type(8))) u16 u16x8;

__device__ __forceinline__ u16 f2bf(float f) {
  unsigned int u = __builtin_bit_cast(unsigned int, f);
  unsigned int r = (u + 0x7FFFu + ((u >> 16) & 1u)) >> 16;
  return (u16)r;
}
__device__ __forceinline__ float bf2f(u16 b) {
  unsigned int u = ((unsigned int)b) << 16;
  return __builtin_bit_cast(float, u);
}
__device__ __forceinline__ bf16x8 load8(const u16* p) {
  return __builtin_bit_cast(bf16x8, *(const u16x8*)p);
}
__device__ __forceinline__ void gl_lds16(const void* g, void* l) {
  __builtin_amdgcn_global_load_lds(
      (const __attribute__((address_space(1))) unsigned int*)g,
      (__attribute__((address_space(3))) unsigned int*)l, 16, 0, 0);
}

// ---------------- f32 -> bf16 convert (hidden_states) ----------------
__global__ __launch_bounds__(256) void convert_x(const float* __restrict__ X,
                                                 u16* __restrict__ Xb) {
  int i = (blockIdx.x * 256 + threadIdx.x) * 4;
  float4 v = *(const float4*)(X + i);
  union { u16 s[4]; uint2 u; } o;
  o.s[0] = f2bf(v.x); o.s[1] = f2bf(v.y); o.s[2] = f2bf(v.z); o.s[3] = f2bf(v.w);
  *(uint2*)(Xb + i) = o.u;
}

// ------------- weight transpose+convert: W[k][n] f32 -> Wt[n][k] bf16 -------------
__global__ __launch_bounds__(256) void transpose_w(
    const float* __restrict__ W0, const float* __restrict__ W1,
    const float* __restrict__ W2, const float* __restrict__ W3,
    u16* __restrict__ T0, u16* __restrict__ T1,
    u16* __restrict__ T2, u16* __restrict__ T3) {
  __shared__ u16 tile[64][65];
  int bz = blockIdx.z;
  const float* W = bz == 0 ? W0 : bz == 1 ? W1 : bz == 2 ? W2 : W3;
  u16* T = bz == 0 ? T0 : bz == 1 ? T1 : bz == 2 ? T2 : T3;
  int n0 = blockIdx.x * 64, k0 = blockIdx.y * 64;
  int t = threadIdx.x;
#pragma unroll 4
  for (int i = 0; i < 16; ++i) {
    int idx = i * 256 + t;
    int r = idx >> 6, c = idx & 63;
    tile[r][c] = f2bf(W[(k0 + r) * 1024 + n0 + c]);
  }
  __syncthreads();
#pragma unroll 4
  for (int i = 0; i < 16; ++i) {
    int idx = i * 256 + t;
    int r = idx >> 6, c = idx & 63;  // r = n-local, c = k-local
    T[(n0 + r) * 1024 + k0 + c] = tile[c][r];
  }
}

// ---------------- bf16 MFMA GEMM: C[M][n] = A[M][K] * W[K][n], B given as Wt[n][k] ----------------
// BMxBN tile, BK=32, 4 waves (2x2), each wave (BM/2)x(BN/2). NMATS=3 -> QKV fused.
template <int BM, int BN, int NMATS, bool OUTF32>
__global__ __launch_bounds__(256) void gemm_bf16(
    const u16* __restrict__ A, const u16* __restrict__ B0,
    const u16* __restrict__ B1, const u16* __restrict__ B2,
    u16* __restrict__ O0, u16* __restrict__ O1, u16* __restrict__ O2,
    float* __restrict__ OF) {
  constexpr int MI = BM / 32, NI = BN / 32;
  constexpr int LA = BM / 64, LB = BN / 64;
  __shared__ u16 As[BM * 32];
  __shared__ u16 Bs[BN * 32];
  const int t = threadIdx.x;
  const int lane = t & 63, w = t >> 6;
  const int g = lane >> 4, li = lane & 15;
  const int n0g = blockIdx.x * BN;
  const int mat = n0g >> 10;
  const int n0 = n0g & 1023;
  const u16* Bp = (NMATS == 1 || mat == 0) ? B0 : (mat == 1 ? B1 : B2);
  const int m0 = blockIdx.y * BM;
  const int wm = (w >> 1) * (BM / 2), wn = (w & 1) * (BN / 2);
  f32x4 acc[MI][NI] = {};
  for (int k0 = 0; k0 < 1024; k0 += 32) {
#pragma unroll
    for (int it = 0; it < LA; ++it) {
      int L = it * 2048 + t * 8;   // bf16 element index within BMx32 tile
      int r = L >> 5, c = L & 31;
      gl_lds16(A + (m0 + r) * 1024 + k0 + c, (char*)As + it * 4096 + w * 1024);
    }
#pragma unroll
    for (int it = 0; it < LB; ++it) {
      int L = it * 2048 + t * 8;
      int r = L >> 5, c = L & 31;
      gl_lds16(Bp + (n0 + r) * 1024 + k0 + c, (char*)Bs + it * 4096 + w * 1024);
    }
    __syncthreads();
    bf16x8 af[MI], bfr[NI];
#pragma unroll
    for (int mi = 0; mi < MI; ++mi) af[mi] = load8(&As[(wm + mi * 16 + li) * 32 + g * 8]);
#pragma unroll
    for (int ni = 0; ni < NI; ++ni) bfr[ni] = load8(&Bs[(wn + ni * 16 + li) * 32 + g * 8]);
#pragma unroll
    for (int mi = 0; mi < MI; ++mi)
#pragma unroll
      for (int ni = 0; ni < NI; ++ni)
        acc[mi][ni] = __builtin_amdgcn_mfma_f32_16x16x32_bf16(af[mi], bfr[ni], acc[mi][ni], 0, 0, 0);
    __syncthreads();
  }
  u16* Ob = (NMATS == 1 || mat == 0) ? O0 : (mat == 1 ? O1 : O2);
#pragma unroll
  for (int mi = 0; mi < MI; ++mi)
#pragma unroll
    for (int ni = 0; ni < NI; ++ni)
#pragma unroll
      for (int r = 0; r < 4; ++r) {
        // verified C/D layout: row = (lane>>4)*4 + r, col = lane&15
        int m = m0 + wm + mi * 16 + g * 4 + r;
        int n = n0 + wn + ni * 16 + li;
        float v = acc[mi][ni][r];
        if (OUTF32) OF[m * 1024 + n] = v;
        else Ob[m * 1024 + n] = f2bf(v);
      }
}

// ---------------- RoPE in-place on bf16 Q,K; fold 1/sqrt(HD) into Q ----------------
__global__ __launch_bounds__(256) void rope_qk(u16* __restrict__ Qb, u16* __restrict__ Kb,
                                               const int* __restrict__ pos_ids) {
  int gid = blockIdx.x * 256 + threadIdx.x;  // one per (s,h,pair)
  int s = gid >> 9;
  int rem = gid & 511;
  int h = rem >> 5, i = rem & 31;
  float pos = (float)pos_ids[s];
  float inv = exp2f(-(float)i * (13.287712379549449f / 32.0f));
  float ang = pos * inv;
  float sn, cs;
  sincosf(ang, &sn, &cs);
  int base = s * 1024 + h * 64 + 2 * i;
  {
    float x0 = bf2f(Qb[base]), x1 = bf2f(Qb[base + 1]);
    Qb[base]     = f2bf((x0 * cs - x1 * sn) * 0.125f);
    Qb[base + 1] = f2bf((x0 * sn + x1 * cs) * 0.125f);
  }
  {
    float x0 = bf2f(Kb[base]), x1 = bf2f(Kb[base + 1]);
    Kb[base]     = f2bf(x0 * cs - x1 * sn);
    Kb[base + 1] = f2bf(x0 * sn + x1 * cs);
  }
}

// ---------------- V transpose: Vb[s][h*64+d] -> Vt[h][d][s] ----------------
__global__ __launch_bounds__(256) void v_transpose(const u16* __restrict__ Vb,
                                                   u16* __restrict__ Vt) {
  __shared__ u16 tile[64][65];
  const int t = threadIdx.x;
  const int s0 = blockIdx.x * 64, h = blockIdx.y;
#pragma unroll 4
  for (int i = 0; i < 16; ++i) {
    int idx = i * 256 + t;
    int r = idx >> 6, c = idx & 63;
    tile[r][c] = Vb[(s0 + r) * 1024 + h * 64 + c];
  }
  __syncthreads();
#pragma unroll 4
  for (int i = 0; i < 16; ++i) {
    int idx = i * 256 + t;
    int d = idx >> 6, sc = idx & 63;
    Vt[h * (64 * 2048) + d * 2048 + s0 + sc] = tile[sc][d];
  }
}

// ---------------- split-K flash attention partial, work-stealing version ----------------
// 2048 blocks x 4 waves. Head = blockIdx.x % 16 -> all blocks of one head land on one
// XCD (16 % 8 == 0), keeping that head's K/V (512 KB) hot in the XCD's 4 MB L2.
// Work item = (qb, c): 256-key chunk c of 16-row q-block qb. 576 items/head,
// 512 waves/head -> each wave does 1-2 balanced items of <=8 K-iterations.
__global__ __launch_bounds__(256) void attn_partial(
    const u16* __restrict__ Qb, const u16* __restrict__ Kb,
    const u16* __restrict__ Vt, const int* __restrict__ amask,
    float* __restrict__ Mpart, float* __restrict__ Lpart, u16* __restrict__ Opart) {
  const int t = threadIdx.x, lane = t & 63, w = t >> 6;
  const int g = lane >> 4, li = lane & 15;
  const int bid = blockIdx.x;
  const int h = bid & 15;                // head -> XCD affinity
  const int wih = (bid >> 4) * 4 + w;    // wave-in-head: 0..511
  __shared__ u16 Plds[4][16][40];        // per-wave P tile, stride 40 kills conflicts
  const u16* Vh = Vt + h * (64 * 2048);
  for (int j = wih; j < NITEMS; j += WPH) {
    // decode chunk c and q-block qb; segment start S_c = 128c - 8c(c-1)
    int c = (j >= 560) ? 7 : (j >= 528) ? 6 : (j >= 480) ? 5 : (j >= 416) ? 4
          : (j >= 336) ? 3 : (j >= 240) ? 2 : (j >= 128) ? 1 : 0;
    int qb = 16 * c + (j - (128 * c - 8 * c * (c - 1)));
    const int qb16 = qb * 16;
    const int kstart = c * KCH;
    const int kend = min(kstart + KCH, qb16 + 16);
    bf16x8 qf0 = load8(Qb + (qb16 + li) * 1024 + h * 64 + 0 + g * 8);
    bf16x8 qf1 = load8(Qb + (qb16 + li) * 1024 + h * 64 + 32 + g * 8);
    f32x4 acc[4] = {};
    float mrow[4] = {-1e30f, -1e30f, -1e30f, -1e30f};
    float lrow[4] = {0.f, 0.f, 0.f, 0.f};
    for (int k0 = kstart; k0 < kend; k0 += 32) {
      f32x4 sc[2] = {};
#pragma unroll
      for (int sub = 0; sub < 2; ++sub) {
        bf16x8 kf0 = load8(Kb + (k0 + sub * 16 + li) * 1024 + h * 64 + 0 + g * 8);
        bf16x8 kf1 = load8(Kb + (k0 + sub * 16 + li) * 1024 + h * 64 + 32 + g * 8);
        sc[sub] = __builtin_amdgcn_mfma_f32_16x16x32_bf16(qf0, kf0, sc[sub], 0, 0, 0);
        sc[sub] = __builtin_amdgcn_mfma_f32_16x16x32_bf16(qf1, kf1, sc[sub], 0, 0, 0);
      }
      // mask + online softmax. Score layout: row(q) = g*4+r, col(key) = li.
      float sv[2][4];
      float tmax[4] = {-1e30f, -1e30f, -1e30f, -1e30f};
#pragma unroll
      for (int sub = 0; sub < 2; ++sub) {
        int key = k0 + sub * 16 + li;
        bool kok = (amask[key] != 0);
#pragma unroll
        for (int r = 0; r < 4; ++r) {
          int q = qb16 + g * 4 + r;
          float v = (kok && key <= q) ? sc[sub][r] : -1e30f;
          sv[sub][r] = v;
          tmax[r] = fmaxf(tmax[r], v);
        }
      }
#pragma unroll
      for (int m = 1; m < 16; m <<= 1)
#pragma unroll
        for (int r = 0; r < 4; ++r) tmax[r] = fmaxf(tmax[r], __shfl_xor(tmax[r], m, 64));
      float alpha[4];
#pragma unroll
      for (int r = 0; r < 4; ++r) {
        float mn = fmaxf(mrow[r], tmax[r]);
        alpha[r] = __expf(mrow[r] - mn);
        mrow[r] = mn;
      }
      float ps[4] = {0.f, 0.f, 0.f, 0.f};
#pragma unroll
      for (int sub = 0; sub < 2; ++sub)
#pragma unroll
        for (int r = 0; r < 4; ++r) {
          float p = __expf(sv[sub][r] - mrow[r]);  // masked -> 0
          ps[r] += p;
          Plds[w][g * 4 + r][sub * 16 + li] = f2bf(p);
        }
#pragma unroll
      for (int m = 1; m < 16; m <<= 1)
#pragma unroll
        for (int r = 0; r < 4; ++r) ps[r] += __shfl_xor(ps[r], m, 64);
#pragma unroll
      for (int r = 0; r < 4; ++r) lrow[r] = lrow[r] * alpha[r] + ps[r];
#pragma unroll
      for (int ti = 0; ti < 4; ++ti)
#pragma unroll
        for (int r = 0; r < 4; ++r) acc[ti][r] *= alpha[r];
      bf16x8 pf = load8(&Plds[w][li][g * 8]);  // same-wave RAW; compiler inserts waits
#pragma unroll
      for (int ti = 0; ti < 4; ++ti) {
        bf16x8 vf = load8(Vh + (ti * 16 + li) * 2048 + k0 + g * 8);
        acc[ti] = __builtin_amdgcn_mfma_f32_16x16x32_bf16(pf, vf, acc[ti], 0, 0, 0);
      }
    }
    const int idx = (h * 128 + qb) * NCH + c;
    if (li == 0) {
#pragma unroll
      for (int r = 0; r < 4; ++r) {
        Mpart[idx * 16 + g * 4 + r] = mrow[r];
        Lpart[idx * 16 + g * 4 + r] = lrow[r];
      }
    }
#pragma unroll
    for (int ti = 0; ti < 4; ++ti)
#pragma unroll
      for (int r = 0; r < 4; ++r)
        Opart[idx * 1024 + (g * 4 + r) * 64 + ti * 16 + li] = f2bf(acc[ti][r]);
  }
}

// ---------------- combine partials -> Ab bf16 [s][h*64+d] ----------------
__global__ __launch_bounds__(256) void attn_combine(
    const float* __restrict__ Mpart, const float* __restrict__ Lpart,
    const u16* __restrict__ Opart, u16* __restrict__ Ab) {
  const int qb = blockIdx.x, h = blockIdx.y;
  const int t = threadIdx.x;
  const int q = t >> 4, dg = t & 15;  // q 0..15, d = dg*4..dg*4+3
  const int nch = qb / 16 + 1;        // ceil((qb*16+16)/256)
  const int base = (h * 128 + qb) * NCH;
  float M = -1e30f;
#pragma unroll
  for (int c = 0; c < NCH; ++c)
    if (c < nch) M = fmaxf(M, Mpart[(base + c) * 16 + q]);
  float L = 0.f;
  float o[4] = {0.f, 0.f, 0.f, 0.f};
#pragma unroll
  for (int c = 0; c < NCH; ++c)
    if (c < nch) {
      float e = __expf(Mpart[(base + c) * 16 + q] - M);
      L += e * Lpart[(base + c) * 16 + q];
      const u16* op = Opart + (base + c) * 1024 + q * 64 + dg * 4;
      uint2 pk = *(const uint2*)op;
      const u16* ps = (const u16*)&pk;
#pragma unroll
      for (int j = 0; j < 4; ++j) o[j] += e * bf2f(ps[j]);
    }
  float inv = 1.f / L;
  u16* dst = Ab + (qb * 16 + q) * 1024 + h * 64 + dg * 4;
  union { u16 s[4]; uint2 u; } ou;
#pragma unroll
  for (int j = 0; j < 4; ++j) ou.s[j] = f2bf(o[j] * inv);
  *(uint2*)dst = ou.u;
}

extern "C" void kernel_launch(void* const* d_in, const int* in_sizes, int n_in,
                              void* d_out, int out_size, void* d_ws, size_t ws_size,
                              hipStream_t stream) {
  const float* X = (const float*)d_in[0];
  const int* amask = (const int*)d_in[1];
  const int* pos = (const int*)d_in[2];
  const float* wq = (const float*)d_in[3];
  const float* wk = (const float*)d_in[4];
  const float* wv = (const float*)d_in[5];
  const float* wo = (const float*)d_in[6];
  float* out = (float*)d_out;
  char* ws = (char*)d_ws;
  // workspace layout (~66 MB total)
  u16* Xb  = (u16*)(ws);                  // 4 MB  X bf16 [2048][1024]
  u16* Wtq = (u16*)(ws + (4u  << 20));    // 2 MB  Wt [n][k]
  u16* Wtk = (u16*)(ws + (6u  << 20));
  u16* Wtv = (u16*)(ws + (8u  << 20));
  u16* Wto = (u16*)(ws + (10u << 20));
  u16* Qb  = (u16*)(ws + (12u << 20));    // 4 MB  [2048][1024] (RoPE'd, x1/8)
  u16* Kb  = (u16*)(ws + (16u << 20));    // 4 MB
  u16* Vb  = (u16*)(ws + (20u << 20));    // 4 MB
  u16* Vt  = (u16*)(ws + (24u << 20));    // 4 MB  [16][64][2048]
  u16* Ab  = (u16*)(ws + (28u << 20));    // 4 MB  attn out bf16
  float* Mpart = (float*)(ws + (32u << 20));  // 1 MB  [16*128*8][16]
  float* Lpart = (float*)(ws + (33u << 20));  // 1 MB
  u16*   Opart = (u16*)(ws + (34u << 20));    // 32 MB [16*128*8][1024]

  convert_x<<<2048, 256, 0, stream>>>(X, Xb);
  transpose_w<<<dim3(16, 16, 4), 256, 0, stream>>>(wq, wk, wv, wo, Wtq, Wtk, Wtv, Wto);
  gemm_bf16<64, 128, 3, false><<<dim3(24, 32), 256, 0, stream>>>(Xb, Wtq, Wtk, Wtv, Qb, Kb, Vb, nullptr);
  rope_qk<<<4096, 256, 0, stream>>>(Qb, Kb, pos);
  v_transpose<<<dim3(32, 16), 256, 0, stream>>>(Vb, Vt);
  attn_partial<<<2048, 256, 0, stream>>>(Qb, Kb, Vt, amask, Mpart, Lpart, Opart);
  attn_combine<<<dim3(128, 16), 256, 0, stream>>>(Mpart, Lpart, Opart, Ab);
  gemm_bf16<64, 64, 1, true><<<dim3(16, 32), 256, 0, stream>>>(Ab, Wto, nullptr, nullptr,
                                                               nullptr, nullptr, nullptr, out);
}

// Round 9
// 117.239 us; speedup vs baseline: 1.6101x; 1.2418x over previous
//
#include <hip/hip_runtime.h>
#include <stdint.h>

#define SEQ 2048
#define DMODEL 1024
#define NHEAD 16
#define HDIM 64
#define KCH 256    // keys per attn work item
#define NCH 8      // max chunks per q-block (SEQ/KCH)
// q-blocks of 32 rows: 64 per head. items per head = sum_c (64-8c) = 288.
#define NIT32 288

typedef unsigned short u16;
typedef __attribute__((ext_vector_type(4))) float f32x4;
typedef __attribute__((ext_vector_type(8))) __bf16 bf16x8;
typedef __attribute__((ext_vector_type(8))) u16 u16x8;

__device__ __forceinline__ u16 f2bf(float f) {
  unsigned int u = __builtin_bit_cast(unsigned int, f);
  unsigned int r = (u + 0x7FFFu + ((u >> 16) & 1u)) >> 16;
  return (u16)r;
}
__device__ __forceinline__ float bf2f(u16 b) {
  unsigned int u = ((unsigned int)b) << 16;
  return __builtin_bit_cast(float, u);
}
__device__ __forceinline__ bf16x8 load8(const u16* p) {
  return __builtin_bit_cast(bf16x8, *(const u16x8*)p);
}
__device__ __forceinline__ void gl_lds16(const void* g, void* l) {
  __builtin_amdgcn_global_load_lds(
      (const __attribute__((address_space(1))) unsigned int*)g,
      (__attribute__((address_space(3))) unsigned int*)l, 16, 0, 0);
}

// ---------------- f32 -> bf16 convert (hidden_states) ----------------
__global__ __launch_bounds__(256) void convert_x(const float* __restrict__ X,
                                                 u16* __restrict__ Xb) {
  int i = (blockIdx.x * 256 + threadIdx.x) * 4;
  float4 v = *(const float4*)(X + i);
  union { u16 s[4]; uint2 u; } o;
  o.s[0] = f2bf(v.x); o.s[1] = f2bf(v.y); o.s[2] = f2bf(v.z); o.s[3] = f2bf(v.w);
  *(uint2*)(Xb + i) = o.u;
}

// ------------- weight transpose+convert: W[k][n] f32 -> Wt[n][k] bf16 -------------
__global__ __launch_bounds__(256) void transpose_w(
    const float* __restrict__ W0, const float* __restrict__ W1,
    const float* __restrict__ W2, const float* __restrict__ W3,
    u16* __restrict__ T0, u16* __restrict__ T1,
    u16* __restrict__ T2, u16* __restrict__ T3) {
  __shared__ u16 tile[64][65];
  int bz = blockIdx.z;
  const float* W = bz == 0 ? W0 : bz == 1 ? W1 : bz == 2 ? W2 : W3;
  u16* T = bz == 0 ? T0 : bz == 1 ? T1 : bz == 2 ? T2 : T3;
  int n0 = blockIdx.x * 64, k0 = blockIdx.y * 64;
  int t = threadIdx.x;
#pragma unroll 4
  for (int i = 0; i < 16; ++i) {
    int idx = i * 256 + t;
    int r = idx >> 6, c = idx & 63;
    tile[r][c] = f2bf(W[(k0 + r) * 1024 + n0 + c]);
  }
  __syncthreads();
#pragma unroll 4
  for (int i = 0; i < 16; ++i) {
    int idx = i * 256 + t;
    int r = idx >> 6, c = idx & 63;  // r = n-local, c = k-local
    T[(n0 + r) * 1024 + k0 + c] = tile[c][r];
  }
}

// ---------------- bf16 MFMA GEMM: C[M][n] = A[M][K] * W[K][n], B given as Wt[n][k] ----------------
template <int BM, int BN, int NMATS, bool OUTF32>
__global__ __launch_bounds__(256) void gemm_bf16(
    const u16* __restrict__ A, const u16* __restrict__ B0,
    const u16* __restrict__ B1, const u16* __restrict__ B2,
    u16* __restrict__ O0, u16* __restrict__ O1, u16* __restrict__ O2,
    float* __restrict__ OF) {
  constexpr int MI = BM / 32, NI = BN / 32;
  constexpr int LA = BM / 64, LB = BN / 64;
  __shared__ u16 As[BM * 32];
  __shared__ u16 Bs[BN * 32];
  const int t = threadIdx.x;
  const int lane = t & 63, w = t >> 6;
  const int g = lane >> 4, li = lane & 15;
  const int n0g = blockIdx.x * BN;
  const int mat = n0g >> 10;
  const int n0 = n0g & 1023;
  const u16* Bp = (NMATS == 1 || mat == 0) ? B0 : (mat == 1 ? B1 : B2);
  const int m0 = blockIdx.y * BM;
  const int wm = (w >> 1) * (BM / 2), wn = (w & 1) * (BN / 2);
  f32x4 acc[MI][NI] = {};
  for (int k0 = 0; k0 < 1024; k0 += 32) {
#pragma unroll
    for (int it = 0; it < LA; ++it) {
      int L = it * 2048 + t * 8;
      int r = L >> 5, c = L & 31;
      gl_lds16(A + (m0 + r) * 1024 + k0 + c, (char*)As + it * 4096 + w * 1024);
    }
#pragma unroll
    for (int it = 0; it < LB; ++it) {
      int L = it * 2048 + t * 8;
      int r = L >> 5, c = L & 31;
      gl_lds16(Bp + (n0 + r) * 1024 + k0 + c, (char*)Bs + it * 4096 + w * 1024);
    }
    __syncthreads();
    bf16x8 af[MI], bfr[NI];
#pragma unroll
    for (int mi = 0; mi < MI; ++mi) af[mi] = load8(&As[(wm + mi * 16 + li) * 32 + g * 8]);
#pragma unroll
    for (int ni = 0; ni < NI; ++ni) bfr[ni] = load8(&Bs[(wn + ni * 16 + li) * 32 + g * 8]);
#pragma unroll
    for (int mi = 0; mi < MI; ++mi)
#pragma unroll
      for (int ni = 0; ni < NI; ++ni)
        acc[mi][ni] = __builtin_amdgcn_mfma_f32_16x16x32_bf16(af[mi], bfr[ni], acc[mi][ni], 0, 0, 0);
    __syncthreads();
  }
  u16* Ob = (NMATS == 1 || mat == 0) ? O0 : (mat == 1 ? O1 : O2);
#pragma unroll
  for (int mi = 0; mi < MI; ++mi)
#pragma unroll
    for (int ni = 0; ni < NI; ++ni)
#pragma unroll
      for (int r = 0; r < 4; ++r) {
        // verified C/D layout: row = (lane>>4)*4 + r, col = lane&15
        int m = m0 + wm + mi * 16 + g * 4 + r;
        int n = n0 + wn + ni * 16 + li;
        float v = acc[mi][ni][r];
        if (OUTF32) OF[m * 1024 + n] = v;
        else Ob[m * 1024 + n] = f2bf(v);
      }
}

// ---------------- RoPE in-place on bf16 Q,K; fold 1/sqrt(HD) into Q ----------------
__global__ __launch_bounds__(256) void rope_qk(u16* __restrict__ Qb, u16* __restrict__ Kb,
                                               const int* __restrict__ pos_ids) {
  int gid = blockIdx.x * 256 + threadIdx.x;  // one per (s,h,pair)
  int s = gid >> 9;
  int rem = gid & 511;
  int h = rem >> 5, i = rem & 31;
  float pos = (float)pos_ids[s];
  float inv = exp2f(-(float)i * (13.287712379549449f / 32.0f));
  float ang = pos * inv;
  float sn, cs;
  sincosf(ang, &sn, &cs);
  int base = s * 1024 + h * 64 + 2 * i;
  {
    float x0 = bf2f(Qb[base]), x1 = bf2f(Qb[base + 1]);
    Qb[base]     = f2bf((x0 * cs - x1 * sn) * 0.125f);
    Qb[base + 1] = f2bf((x0 * sn + x1 * cs) * 0.125f);
  }
  {
    float x0 = bf2f(Kb[base]), x1 = bf2f(Kb[base + 1]);
    Kb[base]     = f2bf(x0 * cs - x1 * sn);
    Kb[base + 1] = f2bf(x0 * sn + x1 * cs);
  }
}

// ---------------- V transpose: Vb[s][h*64+d] -> Vt[h][d][s] ----------------
__global__ __launch_bounds__(256) void v_transpose(const u16* __restrict__ Vb,
                                                   u16* __restrict__ Vt) {
  __shared__ u16 tile[64][65];
  const int t = threadIdx.x;
  const int s0 = blockIdx.x * 64, h = blockIdx.y;
#pragma unroll 4
  for (int i = 0; i < 16; ++i) {
    int idx = i * 256 + t;
    int r = idx >> 6, c = idx & 63;
    tile[r][c] = Vb[(s0 + r) * 1024 + h * 64 + c];
  }
  __syncthreads();
#pragma unroll 4
  for (int i = 0; i < 16; ++i) {
    int idx = i * 256 + t;
    int d = idx >> 6, sc = idx & 63;
    Vt[h * (64 * 2048) + d * 2048 + s0 + sc] = tile[sc][d];
  }
}

// ---------------- split-K flash attention partial: QBLK=32, KVBLK=64 ----------------
// 1152 blocks x 4 waves = 288 waves/head = exactly 1 work item per wave.
// head = bid & 15 -> all blocks of a head on one XCD (1152 % 16 == 0), K/V L2-hot.
// Per 64-key iteration: 32 MFMAs amortize ONE 4-stage shfl chain per (a, max|sum);
// the 4 key-subtiles fold in-lane first, and the two q-subtile chains give ILP.
__global__ __launch_bounds__(256) void attn_partial(
    const u16* __restrict__ Qb, const u16* __restrict__ Kb,
    const u16* __restrict__ Vt, const int* __restrict__ amask,
    float* __restrict__ Mpart, float* __restrict__ Lpart, u16* __restrict__ Opart) {
  const int t = threadIdx.x, lane = t & 63, w = t >> 6;
  const int g = lane >> 4, li = lane & 15;
  const int bid = blockIdx.x;
  const int h = bid & 15;
  const int j = (bid >> 4) * 4 + w;  // 0..287
  __shared__ u16 Plds[4][2][16][72];  // per-wave P tile [a][q16][64+8pad]
  const u16* Vh = Vt + h * (64 * 2048);
  // decode chunk c, q-block qb (32 rows); segment start S_c = 64c - 4c(c-1)
  const int c = (j >= 280) ? 7 : (j >= 264) ? 6 : (j >= 240) ? 5 : (j >= 208) ? 4
              : (j >= 168) ? 3 : (j >= 120) ? 2 : (j >= 64) ? 1 : 0;
  const int qb = 8 * c + (j - (64 * c - 4 * c * (c - 1)));
  const int q0 = qb * 32;
  const int kstart = c * KCH;
  const int kend = min(kstart + KCH, q0 + 32);
  bf16x8 qf[2][2];
#pragma unroll
  for (int a = 0; a < 2; ++a)
#pragma unroll
    for (int hf = 0; hf < 2; ++hf)
      qf[a][hf] = load8(Qb + (q0 + a * 16 + li) * 1024 + h * 64 + hf * 32 + g * 8);
  f32x4 acc[2][4] = {};
  float mrow[2][4], lrow[2][4];
#pragma unroll
  for (int a = 0; a < 2; ++a)
#pragma unroll
    for (int r = 0; r < 4; ++r) { mrow[a][r] = -1e30f; lrow[a][r] = 0.f; }
  for (int k0 = kstart; k0 < kend; k0 += 64) {
    f32x4 sc[2][4] = {};
#pragma unroll
    for (int s = 0; s < 4; ++s) {
      bf16x8 kf0 = load8(Kb + (k0 + s * 16 + li) * 1024 + h * 64 + 0 + g * 8);
      bf16x8 kf1 = load8(Kb + (k0 + s * 16 + li) * 1024 + h * 64 + 32 + g * 8);
#pragma unroll
      for (int a = 0; a < 2; ++a) {
        sc[a][s] = __builtin_amdgcn_mfma_f32_16x16x32_bf16(qf[a][0], kf0, sc[a][s], 0, 0, 0);
        sc[a][s] = __builtin_amdgcn_mfma_f32_16x16x32_bf16(qf[a][1], kf1, sc[a][s], 0, 0, 0);
      }
    }
    // mask + in-lane max over the 4 key-subtiles. Score layout: q = a*16+g*4+r, key = s*16+li.
    float sv[2][4][4];
    float tmax[2][4];
#pragma unroll
    for (int a = 0; a < 2; ++a)
#pragma unroll
      for (int r = 0; r < 4; ++r) tmax[a][r] = -1e30f;
#pragma unroll
    for (int s = 0; s < 4; ++s) {
      int key = k0 + s * 16 + li;
      bool kok = (amask[key] != 0);
#pragma unroll
      for (int a = 0; a < 2; ++a)
#pragma unroll
        for (int r = 0; r < 4; ++r) {
          int q = q0 + a * 16 + g * 4 + r;
          float v = (kok && key <= q) ? sc[a][s][r] : -1e30f;
          sv[a][s][r] = v;
          tmax[a][r] = fmaxf(tmax[a][r], v);
        }
    }
#pragma unroll
    for (int m = 1; m < 16; m <<= 1)
#pragma unroll
      for (int a = 0; a < 2; ++a)
#pragma unroll
        for (int r = 0; r < 4; ++r)
          tmax[a][r] = fmaxf(tmax[a][r], __shfl_xor(tmax[a][r], m, 64));
    float alpha[2][4];
#pragma unroll
    for (int a = 0; a < 2; ++a)
#pragma unroll
      for (int r = 0; r < 4; ++r) {
        float mn = fmaxf(mrow[a][r], tmax[a][r]);
        alpha[a][r] = __expf(mrow[a][r] - mn);
        mrow[a][r] = mn;
      }
    float ps[2][4] = {};
#pragma unroll
    for (int s = 0; s < 4; ++s)
#pragma unroll
      for (int a = 0; a < 2; ++a)
#pragma unroll
        for (int r = 0; r < 4; ++r) {
          float p = __expf(sv[a][s][r] - mrow[a][r]);  // masked -> 0
          ps[a][r] += p;
          Plds[w][a][g * 4 + r][s * 16 + li] = f2bf(p);
        }
#pragma unroll
    for (int m = 1; m < 16; m <<= 1)
#pragma unroll
      for (int a = 0; a < 2; ++a)
#pragma unroll
        for (int r = 0; r < 4; ++r) ps[a][r] += __shfl_xor(ps[a][r], m, 64);
#pragma unroll
    for (int a = 0; a < 2; ++a)
#pragma unroll
      for (int r = 0; r < 4; ++r) lrow[a][r] = lrow[a][r] * alpha[a][r] + ps[a][r];
#pragma unroll
    for (int a = 0; a < 2; ++a)
#pragma unroll
      for (int ti = 0; ti < 4; ++ti)
#pragma unroll
        for (int r = 0; r < 4; ++r) acc[a][ti][r] *= alpha[a][r];
    // P A-fragments from LDS (same-wave RAW; compiler inserts waits)
    bf16x8 pf[2][2];
#pragma unroll
    for (int a = 0; a < 2; ++a)
#pragma unroll
      for (int ks = 0; ks < 2; ++ks)
        pf[a][ks] = load8(&Plds[w][a][li][ks * 32 + g * 8]);
#pragma unroll
    for (int ti = 0; ti < 4; ++ti) {
      bf16x8 vf0 = load8(Vh + (ti * 16 + li) * 2048 + k0 + 0 + g * 8);
      bf16x8 vf1 = load8(Vh + (ti * 16 + li) * 2048 + k0 + 32 + g * 8);
#pragma unroll
      for (int a = 0; a < 2; ++a) {
        acc[a][ti] = __builtin_amdgcn_mfma_f32_16x16x32_bf16(pf[a][0], vf0, acc[a][ti], 0, 0, 0);
        acc[a][ti] = __builtin_amdgcn_mfma_f32_16x16x32_bf16(pf[a][1], vf1, acc[a][ti], 0, 0, 0);
      }
    }
  }
  const int idx = (h * 64 + qb) * NCH + c;
  if (li == 0) {
#pragma unroll
    for (int a = 0; a < 2; ++a)
#pragma unroll
      for (int r = 0; r < 4; ++r) {
        Mpart[idx * 32 + a * 16 + g * 4 + r] = mrow[a][r];
        Lpart[idx * 32 + a * 16 + g * 4 + r] = lrow[a][r];
      }
  }
#pragma unroll
  for (int a = 0; a < 2; ++a)
#pragma unroll
    for (int ti = 0; ti < 4; ++ti)
#pragma unroll
      for (int r = 0; r < 4; ++r)
        Opart[idx * 2048 + (a * 16 + g * 4 + r) * 64 + ti * 16 + li] = f2bf(acc[a][ti][r]);
}

// ---------------- combine partials -> Ab bf16 [s][h*64+d] ----------------
__global__ __launch_bounds__(256) void attn_combine(
    const float* __restrict__ Mpart, const float* __restrict__ Lpart,
    const u16* __restrict__ Opart, u16* __restrict__ Ab) {
  const int qb = blockIdx.x, h = blockIdx.y;  // qb: 32-row block, 0..63
  const int t = threadIdx.x;
  const int q = t >> 3, dg = t & 7;  // q 0..31, d = dg*8..dg*8+7
  const int nch = qb / 8 + 1;        // ceil((qb*32+32)/256)
  const int base = (h * 64 + qb) * NCH;
  float M = -1e30f;
#pragma unroll
  for (int c = 0; c < NCH; ++c)
    if (c < nch) M = fmaxf(M, Mpart[(base + c) * 32 + q]);
  float L = 0.f;
  float o[8] = {};
#pragma unroll
  for (int c = 0; c < NCH; ++c)
    if (c < nch) {
      float e = __expf(Mpart[(base + c) * 32 + q] - M);
      L += e * Lpart[(base + c) * 32 + q];
      uint4 pk = *(const uint4*)(Opart + (base + c) * 2048 + q * 64 + dg * 8);
      const u16* ps = (const u16*)&pk;
#pragma unroll
      for (int jj = 0; jj < 8; ++jj) o[jj] += e * bf2f(ps[jj]);
    }
  float inv = 1.f / L;
  u16* dst = Ab + (qb * 32 + q) * 1024 + h * 64 + dg * 8;
  union { u16 s[8]; uint4 u; } ou;
#pragma unroll
  for (int jj = 0; jj < 8; ++jj) ou.s[jj] = f2bf(o[jj] * inv);
  *(uint4*)dst = ou.u;
}

extern "C" void kernel_launch(void* const* d_in, const int* in_sizes, int n_in,
                              void* d_out, int out_size, void* d_ws, size_t ws_size,
                              hipStream_t stream) {
  const float* X = (const float*)d_in[0];
  const int* amask = (const int*)d_in[1];
  const int* pos = (const int*)d_in[2];
  const float* wq = (const float*)d_in[3];
  const float* wk = (const float*)d_in[4];
  const float* wv = (const float*)d_in[5];
  const float* wo = (const float*)d_in[6];
  float* out = (float*)d_out;
  char* ws = (char*)d_ws;
  // workspace layout (~66 MB total)
  u16* Xb  = (u16*)(ws);                  // 4 MB  X bf16 [2048][1024]
  u16* Wtq = (u16*)(ws + (4u  << 20));    // 2 MB  Wt [n][k]
  u16* Wtk = (u16*)(ws + (6u  << 20));
  u16* Wtv = (u16*)(ws + (8u  << 20));
  u16* Wto = (u16*)(ws + (10u << 20));
  u16* Qb  = (u16*)(ws + (12u << 20));    // 4 MB  [2048][1024] (RoPE'd, x1/8)
  u16* Kb  = (u16*)(ws + (16u << 20));    // 4 MB
  u16* Vb  = (u16*)(ws + (20u << 20));    // 4 MB
  u16* Vt  = (u16*)(ws + (24u << 20));    // 4 MB  [16][64][2048]
  u16* Ab  = (u16*)(ws + (28u << 20));    // 4 MB  attn out bf16
  float* Mpart = (float*)(ws + (32u << 20));  // 1 MB  [16*64*8][32]
  float* Lpart = (float*)(ws + (33u << 20));  // 1 MB
  u16*   Opart = (u16*)(ws + (34u << 20));    // 32 MB [16*64*8][2048]

  convert_x<<<2048, 256, 0, stream>>>(X, Xb);
  transpose_w<<<dim3(16, 16, 4), 256, 0, stream>>>(wq, wk, wv, wo, Wtq, Wtk, Wtv, Wto);
  gemm_bf16<64, 128, 3, false><<<dim3(24, 32), 256, 0, stream>>>(Xb, Wtq, Wtk, Wtv, Qb, Kb, Vb, nullptr);
  rope_qk<<<4096, 256, 0, stream>>>(Qb, Kb, pos);
  v_transpose<<<dim3(32, 16), 256, 0, stream>>>(Vb, Vt);
  attn_partial<<<1152, 256, 0, stream>>>(Qb, Kb, Vt, amask, Mpart, Lpart, Opart);
  attn_combine<<<dim3(64, 16), 256, 0, stream>>>(Mpart, Lpart, Opart, Ab);
  gemm_bf16<64, 64, 1, true><<<dim3(16, 32), 256, 0, stream>>>(Ab, Wto, nullptr, nullptr,
                                                               nullptr, nullptr, nullptr, out);
}